// Round 2
// baseline (444.386 us; speedup 1.0000x reference)
//
#include <hip/hip_runtime.h>

// (B,T,D) = (128, 1024, 64), fp32. out[i][j][t] = prod_{u<=t} (1 + <dX_i(u-1),dY_j(u-1)>/dt)
constexpr int BX    = 128;
constexpr int TT    = 1024;
constexpr int DDIM  = 64;
constexpr int NPAIR = BX * BX;          // 16384
constexpr float DT_INV = 1023.0f;       // 1/dt

// XOR-rotate swizzled LDS index: row stride 64 (no pad, 64KB total for 2 ping-pong
// buffers x 2 arrays), rotation breaks the power-of-2 bank aliasing:
//   x-reads: 4 addrs, 16-way broadcast, disjoint bank quads -> conflict-free
//   y-reads: 16 addrs, 2-way bank alias -> free (m136)
__device__ __forceinline__ int sidx(int row, int col) {
    return (row << 6) + ((col + (row << 2)) & 63);
}

template<int LCH>
__global__ __launch_bounds__(256, 1) void zchunk_kernel(const float* __restrict__ X,
                                                        const float* __restrict__ Y,
                                                        float* __restrict__ out,
                                                        float* __restrict__ P)
{
    __shared__ float smX[2][64 * 64];
    __shared__ float smY[2][64 * 64];
    constexpr int NCH = TT / LCH;

    const int i0 = blockIdx.x * 64;
    const int j0 = blockIdx.y * 64;
    const int t0 = blockIdx.z * LCH;
    const int tid = (int)threadIdx.x;
    const int ti = tid >> 4;        // 0..15
    const int tj = tid & 15;        // 0..15
    const int col4 = tj << 2;

    float4 dx[4], dy[4];            // prefetch registers (diffs for one time step)

    // load diffs for source step s into dx/dy (clamped: s=-1 -> zero diff; s=1023 -> dead value)
    auto load_diffs = [&](int s) {
        const int sa = s < 0 ? 0 : s;
        const int sb = s < 0 ? 0 : (s + 1 < TT ? s + 1 : TT - 1);
#pragma unroll
        for (int k = 0; k < 4; ++k) {
            const float* xp = X + (size_t)(i0 + ti + 16 * k) * (TT * DDIM) + col4;
            const float4 a = *(const float4*)(xp + sa * DDIM);
            const float4 b = *(const float4*)(xp + sb * DDIM);
            dx[k] = make_float4(b.x - a.x, b.y - a.y, b.z - a.z, b.w - a.w);
            const float* yp = Y + (size_t)(j0 + ti + 16 * k) * (TT * DDIM) + col4;
            const float4 c = *(const float4*)(yp + sa * DDIM);
            const float4 d = *(const float4*)(yp + sb * DDIM);
            dy[k] = make_float4(d.x - c.x, d.y - c.y, d.z - c.z, d.w - c.w);
        }
    };
    auto store_stage = [&](int buf) {
#pragma unroll
        for (int k = 0; k < 4; ++k) {
            const int r = ti + 16 * k;
            *(float4*)&smX[buf][sidx(r, col4)] = dx[k];
            *(float4*)&smY[buf][sidx(r, col4)] = dy[k];
        }
    };

    load_diffs(t0 - 1);             // source for step h=0
    store_stage(0);

    float cum[4][4];
#pragma unroll
    for (int a = 0; a < 4; ++a)
#pragma unroll
        for (int b = 0; b < 4; ++b) cum[a][b] = 1.f;

    float* obase[4][4];
#pragma unroll
    for (int a = 0; a < 4; ++a)
#pragma unroll
        for (int b = 0; b < 4; ++b)
            obase[a][b] = out + (size_t)((i0 + ti + 16 * a) * BX + (j0 + tj + 16 * b)) * TT + t0;

    __syncthreads();

#pragma unroll 2
    for (int h = 0; h < LCH; ++h) {
        const int cur = h & 1;
        // prefetch next step's diffs (latency hidden under the 1024-FMA dot loop)
        load_diffs(t0 + h);

        float d[4][4];
#pragma unroll
        for (int a = 0; a < 4; ++a)
#pragma unroll
            for (int b = 0; b < 4; ++b) d[a][b] = 0.f;

#pragma unroll
        for (int dd = 0; dd < DDIM; dd += 4) {
            float4 xv[4], yv[4];
#pragma unroll
            for (int a = 0; a < 4; ++a) xv[a] = *(const float4*)&smX[cur][sidx(ti + 16 * a, dd)];
#pragma unroll
            for (int b = 0; b < 4; ++b) yv[b] = *(const float4*)&smY[cur][sidx(tj + 16 * b, dd)];
#pragma unroll
            for (int a = 0; a < 4; ++a)
#pragma unroll
                for (int b = 0; b < 4; ++b) {
                    d[a][b] = fmaf(xv[a].x, yv[b].x, d[a][b]);
                    d[a][b] = fmaf(xv[a].y, yv[b].y, d[a][b]);
                    d[a][b] = fmaf(xv[a].z, yv[b].z, d[a][b]);
                    d[a][b] = fmaf(xv[a].w, yv[b].w, d[a][b]);
                }
        }

        store_stage(cur ^ 1);       // hand prefetched step to the other buffer
        __syncthreads();            // single barrier per step (ping-pong)

#pragma unroll
        for (int a = 0; a < 4; ++a)
#pragma unroll
            for (int b = 0; b < 4; ++b) {
                cum[a][b] *= fmaf(d[a][b], DT_INV, 1.f);
                obase[a][b][h] = cum[a][b];   // 4B stores; 32B/pair/chunk, sector-aligned
            }
    }

    // chunk-total products, layout P[pair][chunk] so the scan vectorizes
    const int c = blockIdx.z;
#pragma unroll
    for (int a = 0; a < 4; ++a)
#pragma unroll
        for (int b = 0; b < 4; ++b) {
            const int pair = (i0 + ti + 16 * a) * BX + (j0 + tj + 16 * b);
            P[(size_t)pair * NCH + c] = cum[a][b];
        }
}

// In-place exclusive prefix product over chunks, per pair (contiguous float4 rows).
template<int NCH>
__global__ __launch_bounds__(256) void scan_kernel(float* __restrict__ P)
{
    const int p = blockIdx.x * 256 + (int)threadIdx.x;
    float* base = P + (size_t)p * NCH;
    float run = 1.f;
#pragma unroll
    for (int k0 = 0; k0 < NCH; k0 += 32) {
        float4 v[8];
#pragma unroll
        for (int k = 0; k < 8; ++k) v[k] = *(float4*)(base + k0 + 4 * k);
#pragma unroll
        for (int k = 0; k < 8; ++k) {
            float a;
            a = v[k].x; v[k].x = run; run *= a;
            a = v[k].y; v[k].y = run; run *= a;
            a = v[k].z; v[k].z = run; run *= a;
            a = v[k].w; v[k].w = run; run *= a;
        }
#pragma unroll
        for (int k = 0; k < 8; ++k) *(float4*)(base + k0 + 4 * k) = v[k];
    }
}

// out[p][t] *= P[p][t/LCH] — fully coalesced float4 pass.
template<int LCH>
__global__ __launch_bounds__(256) void scale_kernel(float* __restrict__ out,
                                                    const float* __restrict__ P)
{
    constexpr int NCH = TT / LCH;
    const size_t g    = (size_t)blockIdx.x * 256 + threadIdx.x;
    const size_t base = g * 4;
    const int p = (int)(base >> 10);
    const int t = (int)(base & (TT - 1));
    const float f = P[(size_t)p * NCH + t / LCH];
    float4 v = *(float4*)(out + base);
    v.x *= f; v.y *= f; v.z *= f; v.w *= f;
    *(float4*)(out + base) = v;
}

extern "C" void kernel_launch(void* const* d_in, const int* in_sizes, int n_in,
                              void* d_out, int out_size, void* d_ws, size_t ws_size,
                              hipStream_t stream)
{
    const float* X = (const float*)d_in[0];   // (128, 1024, 64) fp32
    const float* Y = (const float*)d_in[1];   // (128, 1024, 64) fp32
    float* out = (float*)d_out;               // (128, 128, 1024) fp32
    float* P   = (float*)d_ws;

    const size_t need8 = (size_t)NPAIR * (TT / 8) * sizeof(float);   // 8 MB
    if (ws_size >= need8) {
        // LCH=8: grid 512 blocks (2 per CU) for latency hiding
        zchunk_kernel<8><<<dim3(2, 2, TT / 8), 256, 0, stream>>>(X, Y, out, P);
        scan_kernel<TT / 8><<<dim3(NPAIR / 256), 256, 0, stream>>>(P);
        scale_kernel<8><<<dim3((NPAIR * TT / 4) / 256), 256, 0, stream>>>(out, P);
    } else {
        // fallback: 2 MB scratch
        zchunk_kernel<32><<<dim3(2, 2, TT / 32), 256, 0, stream>>>(X, Y, out, P);
        scan_kernel<TT / 32><<<dim3(NPAIR / 256), 256, 0, stream>>>(P);
        scale_kernel<32><<<dim3((NPAIR * TT / 4) / 256), 256, 0, stream>>>(out, P);
    }
}